// Round 1
// baseline (35.189 us; speedup 1.0000x reference)
//
#include <hip/hip_runtime.h>

// SceneContraction: f(x) = x if ||x||<1 else (2 - 1/||x||) x/||x||
// cov' = J cov J^T for ||x||>=1, cov otherwise, with J = s I + c x x^T,
//   s = (2n-1)/n^2, c = 2(1-n)/n^4, n = ||x||.
// Memory-bound: 96 B/point, N = 2e6 -> 192 MB.

__global__ __launch_bounds__(256) void scene_contraction_kernel(
    const float* __restrict__ means,
    const float* __restrict__ cov,
    float* __restrict__ out_means,
    float* __restrict__ out_cov,
    int n)
{
    int i = blockIdx.x * blockDim.x + threadIdx.x;
    if (i >= n) return;

    const long mbase = 3L * i;
    const long cbase = 9L * i;

    const float x = means[mbase + 0];
    const float y = means[mbase + 1];
    const float z = means[mbase + 2];

    const float c00 = cov[cbase + 0];
    const float c01 = cov[cbase + 1];
    const float c02 = cov[cbase + 2];
    const float c10 = cov[cbase + 3];
    const float c11 = cov[cbase + 4];
    const float c12 = cov[cbase + 5];
    const float c20 = cov[cbase + 6];
    const float c21 = cov[cbase + 7];
    const float c22 = cov[cbase + 8];

    const float n2 = x * x + y * y + z * z;
    const bool inside = (n2 < 1.0f);

    // Contracted path (garbage if n2 ~ 0, but then we select the identity path).
    const float nrm  = sqrtf(n2);
    const float inv  = 1.0f / nrm;
    const float f    = (2.0f - inv) * inv;          // (2 - 1/n)/n
    const float s    = (2.0f * nrm - 1.0f) * inv * inv;  // (2n-1)/n^2
    const float c    = 2.0f * (1.0f - nrm) / (n2 * n2);  // 2(1-n)/n^4

    const float ox = inside ? x : f * x;
    const float oy = inside ? y : f * y;
    const float oz = inside ? z : f * z;

    // u = C x
    const float u0 = c00 * x + c01 * y + c02 * z;
    const float u1 = c10 * x + c11 * y + c12 * z;
    const float u2 = c20 * x + c21 * y + c22 * z;
    const float q  = x * u0 + y * u1 + z * u2;     // x^T C x

    const float s2  = s * s;
    const float sc  = s * c;
    const float c2q = c * c * q;

    const float t00 = s2 * c00 + sc * (u0 * x + x * u0) + c2q * x * x;
    const float t01 = s2 * c01 + sc * (u0 * y + x * u1) + c2q * x * y;
    const float t02 = s2 * c02 + sc * (u0 * z + x * u2) + c2q * x * z;
    const float t10 = s2 * c10 + sc * (u1 * x + y * u0) + c2q * y * x;
    const float t11 = s2 * c11 + sc * (u1 * y + y * u1) + c2q * y * y;
    const float t12 = s2 * c12 + sc * (u1 * z + y * u2) + c2q * y * z;
    const float t20 = s2 * c20 + sc * (u2 * x + z * u0) + c2q * z * x;
    const float t21 = s2 * c21 + sc * (u2 * y + z * u1) + c2q * z * y;
    const float t22 = s2 * c22 + sc * (u2 * z + z * u2) + c2q * z * z;

    out_means[mbase + 0] = ox;
    out_means[mbase + 1] = oy;
    out_means[mbase + 2] = oz;

    out_cov[cbase + 0] = inside ? c00 : t00;
    out_cov[cbase + 1] = inside ? c01 : t01;
    out_cov[cbase + 2] = inside ? c02 : t02;
    out_cov[cbase + 3] = inside ? c10 : t10;
    out_cov[cbase + 4] = inside ? c11 : t11;
    out_cov[cbase + 5] = inside ? c12 : t12;
    out_cov[cbase + 6] = inside ? c20 : t20;
    out_cov[cbase + 7] = inside ? c21 : t21;
    out_cov[cbase + 8] = inside ? c22 : t22;
}

extern "C" void kernel_launch(void* const* d_in, const int* in_sizes, int n_in,
                              void* d_out, int out_size, void* d_ws, size_t ws_size,
                              hipStream_t stream) {
    const float* means = (const float*)d_in[0];   // [N,3]
    const float* cov   = (const float*)d_in[1];   // [N,3,3]
    const int n = in_sizes[0] / 3;

    float* out_means = (float*)d_out;                  // [N,3]
    float* out_cov   = (float*)d_out + (size_t)n * 3;  // [N,3,3]

    const int block = 256;
    const int grid  = (n + block - 1) / block;
    hipLaunchKernelGGL(scene_contraction_kernel, dim3(grid), dim3(block), 0, stream,
                       means, cov, out_means, out_cov, n);
}

// Round 2
// 34.894 us; speedup vs baseline: 1.0084x; 1.0084x over previous
//
#include <hip/hip_runtime.h>

// SceneContraction: f(x) = x if ||x||<1 else (2 - 1/||x||) x/||x||
// cov' = J cov J^T for ||x||>=1 (J = s I + c x x^T, s=(2n-1)/n^2, c=2(1-n)/n^4),
// cov otherwise.
// Memory-bound: 96 B/point, N=2e6 -> 192 MB logical traffic.
// R1: LDS-staged float4 coalesced loads/stores (G13). Per 256-pt block:
//   means chunk 768 f32 (192 float4), cov chunk 2304 f32 (576 float4) = 3 f4/thread.
//   LDS reads at float-stride 3 / 9 are 2-way bank aliasing only (free, m136).

#define BLOCK 256

__global__ __launch_bounds__(BLOCK) void scene_contraction_kernel(
    const float* __restrict__ means,
    const float* __restrict__ cov,
    float* __restrict__ out_means,
    float* __restrict__ out_cov,
    int n)
{
    __shared__ float sm[BLOCK * 3];   // 3072 B
    __shared__ float sc[BLOCK * 9];   // 9216 B

    const int t  = threadIdx.x;
    const long p0 = (long)blockIdx.x * BLOCK;
    const int npts = (int)min((long)BLOCK, (long)n - p0);
    if (npts <= 0) return;

    // ---- coalesced load: means chunk (floats [3*p0, 3*p0 + 3*npts)) ----
    {
        const int nf = 3 * npts;
        const int nq = nf >> 2;
        const float4* g4 = (const float4*)(means + 3L * p0);  // 16B-aligned: 12*p0 bytes, p0 % 4 == 0
        float4* s4 = (float4*)sm;
        for (int q = t; q < nq; q += BLOCK) s4[q] = g4[q];
        for (int r = (nq << 2) + t; r < nf; r += BLOCK) sm[r] = means[3L * p0 + r];
    }
    // ---- coalesced load: cov chunk (floats [9*p0, 9*p0 + 9*npts)) ----
    {
        const int nf = 9 * npts;
        const int nq = nf >> 2;
        const float4* g4 = (const float4*)(cov + 9L * p0);
        float4* s4 = (float4*)sc;
        for (int q = t; q < nq; q += BLOCK) s4[q] = g4[q];
        for (int r = (nq << 2) + t; r < nf; r += BLOCK) sc[r] = cov[9L * p0 + r];
    }
    __syncthreads();

    const bool active = (t < npts);
    float ox=0, oy=0, oz=0;
    float t00=0,t01=0,t02=0,t10=0,t11=0,t12=0,t20=0,t21=0,t22=0;

    if (active) {
        const float x = sm[3*t + 0];
        const float y = sm[3*t + 1];
        const float z = sm[3*t + 2];

        const float c00 = sc[9*t + 0];
        const float c01 = sc[9*t + 1];
        const float c02 = sc[9*t + 2];
        const float c10 = sc[9*t + 3];
        const float c11 = sc[9*t + 4];
        const float c12 = sc[9*t + 5];
        const float c20 = sc[9*t + 6];
        const float c21 = sc[9*t + 7];
        const float c22 = sc[9*t + 8];

        const float n2 = x*x + y*y + z*z;
        const bool inside = (n2 < 1.0f);

        const float nrm = sqrtf(n2);
        const float inv = 1.0f / nrm;
        const float f   = (2.0f - inv) * inv;                 // (2 - 1/n)/n
        const float s   = (2.0f * nrm - 1.0f) * inv * inv;    // (2n-1)/n^2
        const float c   = 2.0f * (1.0f - nrm) / (n2 * n2);    // 2(1-n)/n^4

        ox = inside ? x : f * x;
        oy = inside ? y : f * y;
        oz = inside ? z : f * z;

        // u = C x
        const float u0 = c00*x + c01*y + c02*z;
        const float u1 = c10*x + c11*y + c12*z;
        const float u2 = c20*x + c21*y + c22*z;
        const float q  = x*u0 + y*u1 + z*u2;    // x^T C x

        const float s2  = s * s;
        const float scc = s * c;
        const float c2q = c * c * q;

        t00 = inside ? c00 : s2*c00 + scc*(u0*x + x*u0) + c2q*x*x;
        t01 = inside ? c01 : s2*c01 + scc*(u0*y + x*u1) + c2q*x*y;
        t02 = inside ? c02 : s2*c02 + scc*(u0*z + x*u2) + c2q*x*z;
        t10 = inside ? c10 : s2*c10 + scc*(u1*x + y*u0) + c2q*y*x;
        t11 = inside ? c11 : s2*c11 + scc*(u1*y + y*u1) + c2q*y*y;
        t12 = inside ? c12 : s2*c12 + scc*(u1*z + y*u2) + c2q*y*z;
        t20 = inside ? c20 : s2*c20 + scc*(u2*x + z*u0) + c2q*z*x;
        t21 = inside ? c21 : s2*c21 + scc*(u2*y + z*u1) + c2q*z*y;
        t22 = inside ? c22 : s2*c22 + scc*(u2*z + z*u2) + c2q*z*z;
    }
    __syncthreads();

    if (active) {
        sm[3*t + 0] = ox;  sm[3*t + 1] = oy;  sm[3*t + 2] = oz;
        sc[9*t + 0] = t00; sc[9*t + 1] = t01; sc[9*t + 2] = t02;
        sc[9*t + 3] = t10; sc[9*t + 4] = t11; sc[9*t + 5] = t12;
        sc[9*t + 6] = t20; sc[9*t + 7] = t21; sc[9*t + 8] = t22;
    }
    __syncthreads();

    // ---- coalesced store ----
    {
        const int nf = 3 * npts;
        const int nq = nf >> 2;
        float4* g4 = (float4*)(out_means + 3L * p0);
        const float4* s4 = (const float4*)sm;
        for (int q = t; q < nq; q += BLOCK) g4[q] = s4[q];
        for (int r = (nq << 2) + t; r < nf; r += BLOCK) out_means[3L * p0 + r] = sm[r];
    }
    {
        const int nf = 9 * npts;
        const int nq = nf >> 2;
        float4* g4 = (float4*)(out_cov + 9L * p0);
        const float4* s4 = (const float4*)sc;
        for (int q = t; q < nq; q += BLOCK) g4[q] = s4[q];
        for (int r = (nq << 2) + t; r < nf; r += BLOCK) out_cov[9L * p0 + r] = sc[r];
    }
}

extern "C" void kernel_launch(void* const* d_in, const int* in_sizes, int n_in,
                              void* d_out, int out_size, void* d_ws, size_t ws_size,
                              hipStream_t stream) {
    const float* means = (const float*)d_in[0];   // [N,3]
    const float* cov   = (const float*)d_in[1];   // [N,3,3]
    const int n = in_sizes[0] / 3;

    float* out_means = (float*)d_out;                  // [N,3]
    float* out_cov   = (float*)d_out + (size_t)n * 3;  // [N,3,3]

    const int grid = (n + BLOCK - 1) / BLOCK;
    hipLaunchKernelGGL(scene_contraction_kernel, dim3(grid), dim3(BLOCK), 0, stream,
                       means, cov, out_means, out_cov, n);
}